// Round 2
// baseline (662.985 us; speedup 1.0000x reference)
//
#include <hip/hip_runtime.h>
#include <hip/hip_bf16.h>

// LSTM cell, fused: gates = [x|h] @ [Wx;Wh] + b ; elementwise -> (h_new, c_new)
// N = 262144 rows, F=64, H=128, K=192, 512 gate columns.
// v3: block = 128 rows x 32 H-cols (4 gate tiles). 4 waves = 4 row-slices, all
// sharing the same B fragments, which are staged to LDS (two 24 KiB phases via
// global_load_lds). K-loop: B from LDS (ds_read_b128, conflict-free), A from
// global (L1/L2), epilogue fused in-register. XCD-aware swizzle keeps the 4
// col-blocks of a row-group on one XCD so A re-reads hit L2.

#define N_ROWS (64 * 4096)
#define HDIM 128
#define FDIM 64
#define KDIM 192
#define NKS 12          // k-steps of 16
#define RBLK 128        // rows per block (4 waves x 32)
#define PH_KS 6         // k-steps per staging phase

typedef __bf16 bf16_t;
typedef __bf16 bf16x8 __attribute__((ext_vector_type(8)));
typedef float f32x16 __attribute__((ext_vector_type(16)));

// ---------------- prologue: swizzle weights fp32 -> bf16 b-frag layout ----------
// Bsw halfword index = ((ks*16 + ct)*64 + lane)*8 + j
//   holds B[k = ks*16 + (lane>>5)*8 + j][n = ct*32 + (lane&31)]
// where B = [Wx;Wh] concat over k (192) and gates concat over n (512).
__global__ void swizzle_weights(const float* __restrict__ Wxi, const float* __restrict__ Whi,
                                const float* __restrict__ Wxf, const float* __restrict__ Whf,
                                const float* __restrict__ Wxc, const float* __restrict__ Whc,
                                const float* __restrict__ Wxo, const float* __restrict__ Who,
                                bf16_t* __restrict__ Bsw) {
    int gid = blockIdx.x * 256 + threadIdx.x;      // 0 .. 12287
    int l  = gid & 63;
    int ct = (gid >> 6) & 15;
    int ks = gid >> 10;
    int kb = ks * 16 + (l >> 5) * 8;               // 8 consecutive k, never straddles 64
    int n  = ct * 32 + (l & 31);
    int g  = n >> 7;
    int c  = n & 127;
    const float* Wx = (g == 0) ? Wxi : (g == 1) ? Wxf : (g == 2) ? Wxc : Wxo;
    const float* Wh = (g == 0) ? Whi : (g == 1) ? Whf : (g == 2) ? Whc : Who;
    bf16x8 v;
#pragma unroll
    for (int j = 0; j < 8; ++j) {
        int k = kb + j;
        float f = (k < FDIM) ? Wx[k * HDIM + c] : Wh[(k - FDIM) * HDIM + c];
        v[j] = (bf16_t)f;
    }
    *(bf16x8*)(Bsw + (long)gid * 8) = v;
}

// ---------------- helpers ----------------
__device__ inline float fast_rcp(float x) { return __builtin_amdgcn_rcpf(x); }
__device__ inline float sigm(float x) {
    x = fminf(fmaxf(x, -30.f), 30.f);
    return fast_rcp(1.f + __expf(-x));
}
__device__ inline float tanh_f(float x) {
    x = fminf(fmaxf(x, -15.f), 15.f);
    float e = __expf(-2.f * x);
    return (1.f - e) * fast_rcp(1.f + e);
}

// ---------------- main fused kernel ----------------
__global__ __launch_bounds__(256, 4)
void lstm_fused(const float* __restrict__ x, const float* __restrict__ h_t,
                const float* __restrict__ c_t,
                const float* __restrict__ b_i, const float* __restrict__ b_f,
                const float* __restrict__ b_c, const float* __restrict__ b_o,
                const bf16_t* __restrict__ Bsw,
                float* __restrict__ h_out, float* __restrict__ c_out) {
    __shared__ bf16_t bsh[PH_KS * 4 * 512];        // 24 KiB: chunk q=(ks6*4+g) -> 1 KiB

    const int tid  = threadIdx.x;
    const int wave = tid >> 6;
    const int lane = tid & 63;

    // XCD-aware bijective swizzle (8192 blocks, 8192%8==0):
    // blocks resident on one XCD get contiguous logical ids -> same row-group,
    // c_blk innermost -> A re-reads served by that XCD's L2.
    const int bid     = blockIdx.x;
    const int logical = ((bid & 7) << 10) | (bid >> 3);
    const int c_blk   = logical & 3;                       // H-col tile 0..3
    const long row_base = (long)(logical >> 2) * RBLK;     // 128-row group

    // A-fragment source: wave owns rows [wave*32, wave*32+32)
    const int r0  = wave * 32 + (lane & 31);
    const int ksl = (lane >> 5) * 8;
    const float* ax = x   + (row_base + r0) * FDIM + ksl;  // 32B aligned
    const float* ah = h_t + (row_base + r0) * HDIM + ksl;  // 32B aligned

    // epilogue coords (C/D: col=lane&31, row=(r&3)+8*(r>>2)+4*(lane>>5))
    const int col   = c_blk * 32 + (lane & 31);            // H column
    const int rhalf = 4 * (lane >> 5);
    const int wrow  = wave * 32;

    // prefetch c_t (16 dwords) + biases -> HBM latency hides under staging+MFMA
    float cpre[16];
#pragma unroll
    for (int r = 0; r < 16; ++r) {
        int row_l = (r & 3) + 8 * (r >> 2) + rhalf;
        cpre[r] = c_t[(row_base + wrow + row_l) * HDIM + col];
    }
    const float bi = b_i[col], bf = b_f[col], bc = b_c[col], bo = b_o[col];

    f32x16 acc0 = {}, acc1 = {}, acc2 = {}, acc3 = {};     // gates i,f,c,o

#pragma unroll
    for (int ph = 0; ph < 2; ++ph) {
        if (ph) __syncthreads();      // protect LDS being re-staged
        // stage 24 x 1 KiB chunks: wave w stages q = w*6 .. w*6+5
#pragma unroll
        for (int i = 0; i < PH_KS; ++i) {
            int q   = wave * PH_KS + i;                    // 0..23 = ks6*4 + g
            int ks6 = q >> 2, g = q & 3;
            // global col-tile ct = g*4 + c_blk, k-step = ph*6 + ks6
            const bf16_t* src = Bsw + ((long)((ph * PH_KS + ks6) * 16 + g * 4 + c_blk) << 9)
                                    + lane * 8;
            bf16_t* dst = bsh + q * 512;                   // wave-uniform base
            __builtin_amdgcn_global_load_lds(
                (const __attribute__((address_space(1))) unsigned int*)src,
                (__attribute__((address_space(3))) unsigned int*)dst, 16, 0, 0);
        }
        __syncthreads();

#pragma unroll
        for (int ks6 = 0; ks6 < PH_KS; ++ks6) {
            int ksg = ph * PH_KS + ks6;
            // A: 8 consecutive fp32 from x (ksg<4) or h, convert to bf16
            const float* ap = (ksg < 4) ? (ax + ksg * 16) : (ah + (ksg - 4) * 16);
            float4 f0 = *(const float4*)(ap);
            float4 f1 = *(const float4*)(ap + 4);
            bf16x8 a;
            a[0] = (bf16_t)f0.x; a[1] = (bf16_t)f0.y; a[2] = (bf16_t)f0.z; a[3] = (bf16_t)f0.w;
            a[4] = (bf16_t)f1.x; a[5] = (bf16_t)f1.y; a[6] = (bf16_t)f1.z; a[7] = (bf16_t)f1.w;

            const bf16_t* bp = bsh + (ks6 * 4) * 512 + lane * 8;   // ds_read_b128 x4
            bf16x8 b0 = *(const bf16x8*)(bp);                      // gate i
            bf16x8 b1 = *(const bf16x8*)(bp + 512);                // gate f
            bf16x8 b2 = *(const bf16x8*)(bp + 1024);               // gate c
            bf16x8 b3 = *(const bf16x8*)(bp + 1536);               // gate o
            acc0 = __builtin_amdgcn_mfma_f32_32x32x16_bf16(a, b0, acc0, 0, 0, 0);
            acc1 = __builtin_amdgcn_mfma_f32_32x32x16_bf16(a, b1, acc1, 0, 0, 0);
            acc2 = __builtin_amdgcn_mfma_f32_32x32x16_bf16(a, b2, acc2, 0, 0, 0);
            acc3 = __builtin_amdgcn_mfma_f32_32x32x16_bf16(a, b3, acc3, 0, 0, 0);
        }
    }

    // epilogue: fused gate math, c_t already in registers
#pragma unroll
    for (int r = 0; r < 16; ++r) {
        int row_l = (r & 3) + 8 * (r >> 2) + rhalf;
        long idx = (row_base + wrow + row_l) * HDIM + col;
        float gi = acc0[r] + bi;
        float gf = acc1[r] + bf;
        float gc = acc2[r] + bc;
        float go = acc3[r] + bo;
        float i_t = sigm(gi);
        float f_t = sigm(gf);
        float ch  = tanh_f(gc);
        float o_t = sigm(go);
        float cn = f_t * cpre[r] + i_t * ch;
        float hn = o_t * tanh_f(cn);
        h_out[idx] = hn;
        c_out[idx] = cn;
    }
}

extern "C" void kernel_launch(void* const* d_in, const int* in_sizes, int n_in,
                              void* d_out, int out_size, void* d_ws, size_t ws_size,
                              hipStream_t stream) {
    const float* x    = (const float*)d_in[0];
    const float* h_t  = (const float*)d_in[1];
    const float* c_t  = (const float*)d_in[2];
    const float* W_xi = (const float*)d_in[3];
    const float* W_hi = (const float*)d_in[4];
    const float* b_i  = (const float*)d_in[5];
    const float* W_xf = (const float*)d_in[6];
    const float* W_hf = (const float*)d_in[7];
    const float* b_f  = (const float*)d_in[8];
    const float* W_xc = (const float*)d_in[9];
    const float* W_hc = (const float*)d_in[10];
    const float* b_c  = (const float*)d_in[11];
    const float* W_xo = (const float*)d_in[12];
    const float* W_ho = (const float*)d_in[13];
    const float* b_o  = (const float*)d_in[14];

    bf16_t* Bsw = (bf16_t*)d_ws;                  // 196608 bytes
    float* h_out = (float*)d_out;
    float* c_out = h_out + (long)N_ROWS * HDIM;

    swizzle_weights<<<48, 256, 0, stream>>>(W_xi, W_hi, W_xf, W_hf,
                                            W_xc, W_hc, W_xo, W_ho, Bsw);
    lstm_fused<<<(N_ROWS / RBLK) * 4, 256, 0, stream>>>(x, h_t, c_t, b_i, b_f, b_c, b_o,
                                                        Bsw, h_out, c_out);
}

// Round 3
// 646.714 us; speedup vs baseline: 1.0252x; 1.0252x over previous
//
#include <hip/hip_runtime.h>
#include <hip/hip_bf16.h>

// LSTM cell, fused: gates = [x|h] @ [Wx;Wh] + b ; elementwise -> (h_new, c_new)
// N = 262144 rows, F=64, H=128, K=192, 512 gate columns.
// v4: weights persistent in REGISTERS. mfma 16x16x32 (acc 4 f32/gate -> 16 AGPR).
// Block = 512 thr = 8 waves covering all 128 H-cols of 16 rows; loops 8 row-tiles.
// Per wave: 24 B-fragments (16 cols x 4 gates x K=192) = 96 VGPR, loaded once.
// Steady state: no B loads, no LDS, no barriers. Per tile: 12 batched A float4
// (addresses identical across the 8 waves -> L1 broadcast), 4 c_t loads, 24 MFMA,
// fused epilogue. Block covers full rows -> minimal HBM write traffic (v3 lesson).

#define N_ROWS (64 * 4096)
#define HDIM 128
#define FDIM 64
#define RPT 16          // rows per tile (MFMA M)
#define TILES 8         // row-tiles per block -> 128 rows/block

typedef __bf16 bf16_t;
typedef __bf16 bf16x8 __attribute__((ext_vector_type(8)));
typedef float f32x4 __attribute__((ext_vector_type(4)));

#define MFMA16(a, b, c) __builtin_amdgcn_mfma_f32_16x16x32_bf16(a, b, c, 0, 0, 0)

// ---------------- prologue: swizzle weights fp32 -> bf16 b-frag layout ----------
// Bsw halfword index = (((ks*4 + g)*8 + w)*64 + lane)*8 + j
//   holds B_g[k = ks*32 + ((lane>>4)&3)*8 + j][H-col c = w*16 + (lane&15)]
// where B_g = [Wx_g; Wh_g] over k (192), g in {i,f,c,o}, w = col-slice 0..7.
__global__ void swizzle_weights(const float* __restrict__ Wxi, const float* __restrict__ Whi,
                                const float* __restrict__ Wxf, const float* __restrict__ Whf,
                                const float* __restrict__ Wxc, const float* __restrict__ Whc,
                                const float* __restrict__ Wxo, const float* __restrict__ Who,
                                bf16_t* __restrict__ Bsw) {
    int gid  = blockIdx.x * 256 + threadIdx.x;   // 0 .. 12287
    int lane = gid & 63;
    int w    = (gid >> 6) & 7;                   // col-slice
    int g    = (gid >> 9) & 3;                   // gate
    int ks   = gid >> 11;                        // k-step of 32, 0..5
    int kb   = ks * 32 + ((lane >> 4) & 3) * 8;  // 8 consecutive k
    int c    = w * 16 + (lane & 15);             // H column 0..127
    const float* Wx = (g == 0) ? Wxi : (g == 1) ? Wxf : (g == 2) ? Wxc : Wxo;
    const float* Wh = (g == 0) ? Whi : (g == 1) ? Whf : (g == 2) ? Whc : Who;
    bf16x8 v;
#pragma unroll
    for (int j = 0; j < 8; ++j) {
        int k = kb + j;
        float f = (k < FDIM) ? Wx[k * HDIM + c] : Wh[(k - FDIM) * HDIM + c];
        v[j] = (bf16_t)f;
    }
    *(bf16x8*)(Bsw + (long)gid * 8) = v;
}

// ---------------- helpers ----------------
__device__ inline float fast_rcp(float x) { return __builtin_amdgcn_rcpf(x); }
// v_exp handles the full range (inf/0) -> no clamps needed
__device__ inline float sigm(float x) { return fast_rcp(1.f + __expf(-x)); }
__device__ inline float tanh_f(float x) { return 1.f - 2.f * fast_rcp(1.f + __expf(2.f * x)); }

__device__ inline bf16x8 cvt8(float4 a, float4 b) {
    bf16x8 r;
    r[0] = (bf16_t)a.x; r[1] = (bf16_t)a.y; r[2] = (bf16_t)a.z; r[3] = (bf16_t)a.w;
    r[4] = (bf16_t)b.x; r[5] = (bf16_t)b.y; r[6] = (bf16_t)b.z; r[7] = (bf16_t)b.w;
    return r;
}

// ---------------- main fused kernel ----------------
__global__ __launch_bounds__(512, 2)
void lstm_fused(const float* __restrict__ x, const float* __restrict__ h_t,
                const float* __restrict__ c_t,
                const float* __restrict__ b_i, const float* __restrict__ b_f,
                const float* __restrict__ b_c, const float* __restrict__ b_o,
                const bf16_t* __restrict__ Bsw,
                float* __restrict__ h_out, float* __restrict__ c_out) {
    const int tid  = threadIdx.x;
    const int wv   = tid >> 6;                   // 0..7: H-col slice
    const int lane = tid & 63;
    const long row0 = (long)blockIdx.x * (RPT * TILES);

    // A-frag coords: row = lane&15, k-group offset = (lane>>4)*8
    const int arow = lane & 15;
    const int kof  = (lane >> 4) * 8;

    // persistent B fragments: 6 k-steps x 4 gates = 24 x bf16x8 (96 VGPR)
    bf16x8 breg[24];
#pragma unroll
    for (int ks = 0; ks < 6; ++ks)
#pragma unroll
        for (int g = 0; g < 4; ++g)
            breg[ks * 4 + g] =
                *(const bf16x8*)(Bsw + ((long)((ks * 4 + g) * 8 + wv) << 9) + lane * 8);

    // epilogue coords (16x16 C/D: col = lane&15, row = (lane>>4)*4 + reg)
    const int col  = wv * 16 + (lane & 15);      // H column
    const int orow = (lane >> 4) * 4;            // output row base for this lane
    const float bi = b_i[col], bff = b_f[col], bcc = b_c[col], boo = b_o[col];

    for (int t = 0; t < TILES; ++t) {
        const long rb = row0 + (long)t * RPT;
        const float* xr = x   + (rb + arow) * FDIM + kof;
        const float* hr = h_t + (rb + arow) * HDIM + kof;

        // batch-issue all independent loads for this tile (12 x float4 + 4 x c_t)
        float4 x0 = *(const float4*)(xr);            // ks0: k = kof..kof+7
        float4 x1 = *(const float4*)(xr + 4);
        float4 x2 = *(const float4*)(xr + 32);       // ks1: k = 32+kof..
        float4 x3 = *(const float4*)(xr + 36);
        float4 h0 = *(const float4*)(hr);            // ks2: k = 64+kof..
        float4 h1 = *(const float4*)(hr + 4);
        float cp[4];
#pragma unroll
        for (int r = 0; r < 4; ++r)
            cp[r] = c_t[(rb + orow + r) * HDIM + col];
        float4 h2 = *(const float4*)(hr + 32);       // ks3
        float4 h3 = *(const float4*)(hr + 36);
        float4 h4 = *(const float4*)(hr + 64);       // ks4
        float4 h5 = *(const float4*)(hr + 68);
        float4 h6 = *(const float4*)(hr + 96);       // ks5
        float4 h7 = *(const float4*)(hr + 100);

        f32x4 acc0 = {}, acc1 = {}, acc2 = {}, acc3 = {};
        bf16x8 a;
        a = cvt8(x0, x1);
        acc0 = MFMA16(a, breg[0],  acc0); acc1 = MFMA16(a, breg[1],  acc1);
        acc2 = MFMA16(a, breg[2],  acc2); acc3 = MFMA16(a, breg[3],  acc3);
        a = cvt8(x2, x3);
        acc0 = MFMA16(a, breg[4],  acc0); acc1 = MFMA16(a, breg[5],  acc1);
        acc2 = MFMA16(a, breg[6],  acc2); acc3 = MFMA16(a, breg[7],  acc3);
        a = cvt8(h0, h1);
        acc0 = MFMA16(a, breg[8],  acc0); acc1 = MFMA16(a, breg[9],  acc1);
        acc2 = MFMA16(a, breg[10], acc2); acc3 = MFMA16(a, breg[11], acc3);
        a = cvt8(h2, h3);
        acc0 = MFMA16(a, breg[12], acc0); acc1 = MFMA16(a, breg[13], acc1);
        acc2 = MFMA16(a, breg[14], acc2); acc3 = MFMA16(a, breg[15], acc3);
        a = cvt8(h4, h5);
        acc0 = MFMA16(a, breg[16], acc0); acc1 = MFMA16(a, breg[17], acc1);
        acc2 = MFMA16(a, breg[18], acc2); acc3 = MFMA16(a, breg[19], acc3);
        a = cvt8(h6, h7);
        acc0 = MFMA16(a, breg[20], acc0); acc1 = MFMA16(a, breg[21], acc1);
        acc2 = MFMA16(a, breg[22], acc2); acc3 = MFMA16(a, breg[23], acc3);

        // fused epilogue: 4 output elements per lane
#pragma unroll
        for (int r = 0; r < 4; ++r) {
            long idx = (rb + orow + r) * HDIM + col;
            float gi = acc0[r] + bi;
            float gf = acc1[r] + bff;
            float gc = acc2[r] + bcc;
            float go = acc3[r] + boo;
            float i_t = sigm(gi);
            float f_t = sigm(gf);
            float ch  = tanh_f(gc);
            float o_t = sigm(go);
            float cn = f_t * cp[r] + i_t * ch;
            float hn = o_t * tanh_f(cn);
            h_out[idx] = hn;
            c_out[idx] = cn;
        }
    }
}

extern "C" void kernel_launch(void* const* d_in, const int* in_sizes, int n_in,
                              void* d_out, int out_size, void* d_ws, size_t ws_size,
                              hipStream_t stream) {
    const float* x    = (const float*)d_in[0];
    const float* h_t  = (const float*)d_in[1];
    const float* c_t  = (const float*)d_in[2];
    const float* W_xi = (const float*)d_in[3];
    const float* W_hi = (const float*)d_in[4];
    const float* b_i  = (const float*)d_in[5];
    const float* W_xf = (const float*)d_in[6];
    const float* W_hf = (const float*)d_in[7];
    const float* b_f  = (const float*)d_in[8];
    const float* W_xc = (const float*)d_in[9];
    const float* W_hc = (const float*)d_in[10];
    const float* b_c  = (const float*)d_in[11];
    const float* W_xo = (const float*)d_in[12];
    const float* W_ho = (const float*)d_in[13];
    const float* b_o  = (const float*)d_in[14];

    bf16_t* Bsw = (bf16_t*)d_ws;                  // 196608 bytes
    float* h_out = (float*)d_out;
    float* c_out = h_out + (long)N_ROWS * HDIM;

    swizzle_weights<<<48, 256, 0, stream>>>(W_xi, W_hi, W_xf, W_hf,
                                            W_xc, W_hc, W_xo, W_ho, Bsw);
    lstm_fused<<<N_ROWS / (RPT * TILES), 512, 0, stream>>>(x, h_t, c_t,
                                                           b_i, b_f, b_c, b_o,
                                                           Bsw, h_out, c_out);
}